// Round 1
// baseline (144.700 us; speedup 1.0000x reference)
//
#include <hip/hip_runtime.h>

// GraphSAGE layer: out = relu(h @ Ws^T + (scatter_mean(h,src,dst)) @ Wn^T + b)
// N=50000, E=800000, dim 128.
// R14: FUSE gather + GEMM. K_B wrote accb (12.8MB) which K4 re-read (12.8MB)
//      => 25.6MB HBM round trip + extra launch. Fused kernel keeps the mean
//      rows in a 17KB LDS A-tile and runs the K=256 MFMA GEMM in-block.
//      B-fragments come straight from global wb (64KB, L2-broadcast) instead
//      of LDS staging, keeping LDS at ~23KB => 7 blocks/CU (28 waves/CU, was
//      12) which also doubles gather-phase latency hiding.
constexpr int N_NODES_C = 50000;
constexpr int N_EDGES_C = 800000;
constexpr int DIM_C     = 128;

constexpr int NBKT  = 196;    // (50000+255)>>8
constexpr int CAP   = 8192;   // bucket capacity; mean fill 4096, sd ~64
constexpr int EPB_S = 8192;   // edges per scatter block
constexpr int NB_SCAT  = 98;  // (800000+8191)/8192
constexpr int NB_WCAST = 2;   // W-cast blocks: one per matrix
constexpr int NB_CASTK = 391; // h-cast blocks: 1024 thr x 16 elems, guarded

constexpr int SUBS    = 4;    // fused blocks per bucket
constexpr int NSUB    = 64;   // nodes per sub-block
constexpr int CAP_SUB = 2048; // sub-block edge capacity; mean 1024, sd ~32

typedef __attribute__((ext_vector_type(8))) short short8;  // 8 bf16, 4 VGPRs
typedef __attribute__((ext_vector_type(4))) float f32x4;
typedef __attribute__((ext_vector_type(2))) float f32x2;

// Workspace layout (bytes), ~25.7 MB used (accb eliminated):
constexpr size_t OFF_HB   = 0;                                   // ushort[N][128]
constexpr size_t OFF_PK   = (size_t)N_NODES_C * DIM_C * 2;       // 12,800,000
constexpr size_t OFF_GC   = OFF_PK + (size_t)NBKT * CAP * 4;     // 19,222,528
constexpr size_t OFF_WB   = OFF_GC + 1024;                       // ushort[2][128][128]
constexpr size_t OFF_H8   = OFF_WB + 2 * DIM_C * DIM_C * 2;      // uchar[N][128] fp8

// round-to-nearest-even f32 -> bf16 bits (finite inputs only)
static __device__ __forceinline__ ushort f2bf(float f) {
  unsigned u = __float_as_uint(f);
  return (ushort)((u + 0x7FFFu + ((u >> 16) & 1u)) >> 16);
}
static __device__ __forceinline__ unsigned pack2(float a, float b) {
  return (unsigned)f2bf(a) | ((unsigned)f2bf(b) << 16);
}
// 4 floats -> 4 packed OCP e4m3 bytes (HW cvt, RNE)
static __device__ __forceinline__ unsigned pk_fp8x4(float4 a) {
  unsigned u = __builtin_amdgcn_cvt_pk_fp8_f32(a.x, a.y, 0u, false);
  return __builtin_amdgcn_cvt_pk_fp8_f32(a.z, a.w, u, true);
}

// --------------------------------------------------------------------------
// K_A: fused bucket scatter + cast(W) + cast(h -> bf16 AND fp8). Unchanged.
// --------------------------------------------------------------------------
__global__ __launch_bounds__(1024) void sage_cast_bucket(
    const float* __restrict__ h, ushort* __restrict__ hb,
    unsigned char* __restrict__ h8,
    const float* __restrict__ Wself, const float* __restrict__ Wneigh,
    ushort* __restrict__ wb,
    const int* __restrict__ src, const int* __restrict__ dst,
    int* __restrict__ gcur, unsigned* __restrict__ packed)
{
  const int b = blockIdx.x;
  const int t = threadIdx.x;
  if (b >= NB_SCAT) {
    if (b < NB_SCAT + NB_WCAST) {
      int m = b - NB_SCAT;                    // 0: Wself, 1: Wneigh
      const float* sp = m ? Wneigh : Wself;
      ushort* dp = wb + (size_t)m * DIM_C * DIM_C;
      size_t i = (size_t)t * 16;              // 1024*16 = 16384 exactly
      float4 a0 = *reinterpret_cast<const float4*>(sp + i);
      float4 a1 = *reinterpret_cast<const float4*>(sp + i + 4);
      float4 a2 = *reinterpret_cast<const float4*>(sp + i + 8);
      float4 a3 = *reinterpret_cast<const float4*>(sp + i + 12);
      uint4 o0, o1;
      o0.x = pack2(a0.x, a0.y); o0.y = pack2(a0.z, a0.w);
      o0.z = pack2(a1.x, a1.y); o0.w = pack2(a1.z, a1.w);
      o1.x = pack2(a2.x, a2.y); o1.y = pack2(a2.z, a2.w);
      o1.z = pack2(a3.x, a3.y); o1.w = pack2(a3.z, a3.w);
      *reinterpret_cast<uint4*>(dp + i)     = o0;
      *reinterpret_cast<uint4*>(dp + i + 8) = o1;
    } else {
      int tid = (b - NB_SCAT - NB_WCAST) * 1024 + t;
      if (tid >= 400000) return;              // 400000*16 = 6.4M elems
      size_t i = (size_t)tid * 16;
      float4 a0 = *reinterpret_cast<const float4*>(h + i);
      float4 a1 = *reinterpret_cast<const float4*>(h + i + 4);
      float4 a2 = *reinterpret_cast<const float4*>(h + i + 8);
      float4 a3 = *reinterpret_cast<const float4*>(h + i + 12);
      uint4 o0, o1;
      o0.x = pack2(a0.x, a0.y); o0.y = pack2(a0.z, a0.w);
      o0.z = pack2(a1.x, a1.y); o0.w = pack2(a1.z, a1.w);
      o1.x = pack2(a2.x, a2.y); o1.y = pack2(a2.z, a2.w);
      o1.z = pack2(a3.x, a3.y); o1.w = pack2(a3.z, a3.w);
      *reinterpret_cast<uint4*>(hb + i)     = o0;
      *reinterpret_cast<uint4*>(hb + i + 8) = o1;
      uint4 q;                                 // 16 fp8 bytes
      q.x = pk_fp8x4(a0); q.y = pk_fp8x4(a1);
      q.z = pk_fp8x4(a2); q.w = pk_fp8x4(a3);
      *reinterpret_cast<uint4*>(h8 + i) = q;
    }
    return;
  }

  __shared__ int      bh[256];       // per-bucket count (padded for scan)
  __shared__ int      excl[256];
  __shared__ int      curb[NBKT];
  __shared__ int      bofsG[NBKT];   // reserved base within bucket region
  __shared__ unsigned sorted[EPB_S]; // 32 KB

  const int e0 = b * EPB_S + t * 8;
  const bool l0 = (e0     < N_EDGES_C);      // E%4==0: int4 valid when base<E
  const bool l1 = (e0 + 4 < N_EDGES_C);

  if (t < 256) bh[t] = 0;
  __syncthreads();

  int4 da, db, sa, sb;
  if (l0) {
    da = *reinterpret_cast<const int4*>(dst + e0);
    sa = *reinterpret_cast<const int4*>(src + e0);
    atomicAdd(&bh[da.x >> 8], 1); atomicAdd(&bh[da.y >> 8], 1);
    atomicAdd(&bh[da.z >> 8], 1); atomicAdd(&bh[da.w >> 8], 1);
  }
  if (l1) {
    db = *reinterpret_cast<const int4*>(dst + e0 + 4);
    sb = *reinterpret_cast<const int4*>(src + e0 + 4);
    atomicAdd(&bh[db.x >> 8], 1); atomicAdd(&bh[db.y >> 8], 1);
    atomicAdd(&bh[db.z >> 8], 1); atomicAdd(&bh[db.w >> 8], 1);
  }
  __syncthreads();

  // exclusive scan of bh[256] by wave 0 (4 bins/lane)
  if (t < 64) {
    int base = t * 4;
    int h0 = bh[base], h1 = bh[base + 1], h2 = bh[base + 2], h3 = bh[base + 3];
    int s = h0 + h1 + h2 + h3;
    int x = s;
#pragma unroll
    for (int d = 1; d < 64; d <<= 1) {
      int y = __shfl_up(x, d, 64);
      if (t >= d) x += y;
    }
    int ex = x - s;
    excl[base]     = ex;
    excl[base + 1] = ex + h0;
    excl[base + 2] = ex + h0 + h1;
    excl[base + 3] = ex + h0 + h1 + h2;
  }
  __syncthreads();

  if (t < NBKT) {
    curb[t]  = excl[t];
    bofsG[t] = (bh[t] > 0) ? atomicAdd(&gcur[t], bh[t]) : 0;
  }
  __syncthreads();

#define PLACE(dd, ss)                                            \
  do {                                                           \
    int p_ = atomicAdd(&curb[(dd) >> 8], 1);                     \
    sorted[p_] = ((unsigned)((dd) & 255) << 16) | (unsigned)(ss);\
  } while (0)
  if (l0) { PLACE(da.x, sa.x); PLACE(da.y, sa.y); PLACE(da.z, sa.z); PLACE(da.w, sa.w); }
  if (l1) { PLACE(db.x, sb.x); PLACE(db.y, sb.y); PLACE(db.z, sb.z); PLACE(db.w, sb.w); }
#undef PLACE
  __syncthreads();

  // coalesced burst write-out: wave w owns buckets w, w+16, ...
  const int w    = t >> 6;
  const int lane = t & 63;
  for (int k = w; k < NBKT; k += 16) {
    int len = bh[k];
    int gb  = bofsG[k];
    if (gb + len > CAP) len = CAP - gb;      // statistically unreachable
    int lb  = excl[k];
    unsigned* outp = packed + (size_t)k * CAP + gb;
    for (int off = lane; off < len; off += 64)
      outp[off] = sorted[lb + off];
  }
}

// --------------------------------------------------------------------------
// K_F: FUSED per-sub-bucket sort + gather-mean + MFMA GEMM + bias + relu.
// Block (bucket b, sub s) owns 64 nodes. 784 x 256thr (4 waves).
// Phase 1: counting sort of the bucket's edges filtered to our rid range.
// Phase 2: gather fp8 rows, 8 lanes/node x uint4; mean -> bf16 LDS A-tile.
// Phase 3: 64x128 GEMM, K=256: self-half A from global hb, neigh-half A
//          from LDS tile; B-fragments from global wb (64KB, L2-broadcast).
// LDS ~23KB => 7 blocks/CU (28 waves/CU) for the latency-bound gather.
// --------------------------------------------------------------------------
__global__ __launch_bounds__(256) void sage_gather_gemm(
    const unsigned* __restrict__ packed, const int* __restrict__ gcur,
    const unsigned char* __restrict__ h8, const ushort* __restrict__ hb,
    const ushort* __restrict__ wb, const float* __restrict__ bias,
    float* __restrict__ out)
{
  __shared__ int    hist[NSUB];
  __shared__ int    excl_s[NSUB];
  __shared__ int    curb[NSUB];
  __shared__ ushort esrc_l[CAP_SUB];        // 4 KB
  __shared__ ushort Al[NSUB][DIM_C + 8];    // 64 x 136 x 2B = 17,408 B
  __shared__ float  bias_l[DIM_C];

  const int b   = blockIdx.x >> 2;     // bucket
  const int sub = blockIdx.x & 3;
  const int rlo = sub * NSUB;
  const int t = threadIdx.x;
  const int count = min(gcur[b], CAP);
  const unsigned* pk = packed + (size_t)b * CAP;
  const int nvec = count >> 2;
  const int ntail = count & 3;

  if (t < NSUB) hist[t] = 0;
  if (t >= 128 && t < 128 + DIM_C) bias_l[t - 128] = bias[t - 128];
  __syncthreads();

  // pass 1: histogram of our rid range (vectorized scan, L2-hot)
  for (int g = t; g < nvec; g += 256) {
    uint4 w4 = *reinterpret_cast<const uint4*>(pk + g * 4);
    int r;
    r = (int)(w4.x >> 16) - rlo; if ((unsigned)r < (unsigned)NSUB) atomicAdd(&hist[r], 1);
    r = (int)(w4.y >> 16) - rlo; if ((unsigned)r < (unsigned)NSUB) atomicAdd(&hist[r], 1);
    r = (int)(w4.z >> 16) - rlo; if ((unsigned)r < (unsigned)NSUB) atomicAdd(&hist[r], 1);
    r = (int)(w4.w >> 16) - rlo; if ((unsigned)r < (unsigned)NSUB) atomicAdd(&hist[r], 1);
  }
  if (t < ntail) {
    int r = (int)(pk[nvec * 4 + t] >> 16) - rlo;
    if ((unsigned)r < (unsigned)NSUB) atomicAdd(&hist[r], 1);
  }
  __syncthreads();

  // exclusive scan of hist[64] by wave 0 (1 bin per lane)
  if (t < 64) {
    int v = hist[t];
    int x = v;
#pragma unroll
    for (int d = 1; d < 64; d <<= 1) {
      int y = __shfl_up(x, d, 64);
      if (t >= d) x += y;
    }
    excl_s[t] = x - v;
    curb[t]   = x - v;
  }
  __syncthreads();

  // pass 2: filtered placement
  for (int g = t; g < nvec; g += 256) {
    uint4 w4 = *reinterpret_cast<const uint4*>(pk + g * 4);
    unsigned ww[4] = {w4.x, w4.y, w4.z, w4.w};
#pragma unroll
    for (int j = 0; j < 4; j++) {
      int r = (int)(ww[j] >> 16) - rlo;
      if ((unsigned)r < (unsigned)NSUB) {
        int p = atomicAdd(&curb[r], 1);
        esrc_l[p] = (ushort)(ww[j] & 0xFFFFu);
      }
    }
  }
  if (t < ntail) {
    unsigned wv = pk[nvec * 4 + t];
    int r = (int)(wv >> 16) - rlo;
    if ((unsigned)r < (unsigned)NSUB) {
      int p = atomicAdd(&curb[r], 1);
      esrc_l[p] = (ushort)(wv & 0xFFFFu);
    }
  }
  __syncthreads();

  // gather: 2 rounds x 32 nodes; 8 lanes per node, 16 fp8 per lane (uint4).
  // Empty nodes (incl. rids past N in bucket 195) write zeros to Al.
  const int c = (t & 7) << 4;
#pragma unroll
  for (int rd = 0; rd < 2; rd++) {
    int lr = rd * 32 + (t >> 3);     // local rid 0..63
    int begin = excl_s[lr];
    int cnt   = hist[lr];
    int end   = begin + cnt;

    float s[16];
#pragma unroll
    for (int j = 0; j < 16; j++) s[j] = 0.f;

#define ACCD(wd, o)                                                \
    do {                                                           \
      f32x2 p_;                                                    \
      p_ = __builtin_amdgcn_cvt_pk_f32_fp8((wd), false);           \
      s[(o)]     += p_.x; s[(o) + 1] += p_.y;                      \
      p_ = __builtin_amdgcn_cvt_pk_f32_fp8((wd), true);            \
      s[(o) + 2] += p_.x; s[(o) + 3] += p_.y;                      \
    } while (0)
#define ACC16(u)                                                   \
    do { ACCD((u).x, 0); ACCD((u).y, 4); ACCD((u).z, 8); ACCD((u).w, 12); } while (0)

    int i = begin;
    for (; i + 3 < end; i += 4) {
      int e0 = esrc_l[i], e1 = esrc_l[i + 1], e2 = esrc_l[i + 2], e3 = esrc_l[i + 3];
      uint4 a  = *reinterpret_cast<const uint4*>(h8 + (size_t)e0 * DIM_C + c);
      uint4 bb = *reinterpret_cast<const uint4*>(h8 + (size_t)e1 * DIM_C + c);
      uint4 d  = *reinterpret_cast<const uint4*>(h8 + (size_t)e2 * DIM_C + c);
      uint4 f  = *reinterpret_cast<const uint4*>(h8 + (size_t)e3 * DIM_C + c);
      ACC16(a); ACC16(bb); ACC16(d); ACC16(f);
    }
    for (; i < end; i++) {
      int e0 = esrc_l[i];
      uint4 a = *reinterpret_cast<const uint4*>(h8 + (size_t)e0 * DIM_C + c);
      ACC16(a);
    }
#undef ACC16
#undef ACCD

    float id = 1.0f / (float)max(cnt, 1);   // == 1/deg[n] by construction
    uint4 o0, o1;
    o0.x = pack2(s[0]  * id, s[1]  * id);
    o0.y = pack2(s[2]  * id, s[3]  * id);
    o0.z = pack2(s[4]  * id, s[5]  * id);
    o0.w = pack2(s[6]  * id, s[7]  * id);
    o1.x = pack2(s[8]  * id, s[9]  * id);
    o1.y = pack2(s[10] * id, s[11] * id);
    o1.z = pack2(s[12] * id, s[13] * id);
    o1.w = pack2(s[14] * id, s[15] * id);
    *reinterpret_cast<uint4*>(&Al[lr][c])     = o0;
    *reinterpret_cast<uint4*>(&Al[lr][c + 8]) = o1;
  }
  __syncthreads();

  // ---- GEMM phase: 64 rows x 128 cols, K=256 ----
  // Layouts (m89/m91-verified): A[m=lane&15][k=quad*8+j];
  // B from W[n][k] with n=lane&15, k=quad*8+j; C/D col=lane&15, row=quad*4+reg.
  const int lane = t & 63;
  const int w    = t >> 6;
  const int am   = lane & 15;
  const int q    = lane >> 4;
  const int n0   = (b << 8) + rlo;

  int r0 = n0 + w * 16 + am; if (r0 >= N_NODES_C) r0 = N_NODES_C - 1;
  const ushort* aph    = hb + (size_t)r0 * DIM_C + q * 8;
  const ushort* bself  = wb + (size_t)am * DIM_C + q * 8;
  const ushort* bneigh = bself + (size_t)DIM_C * DIM_C;

  f32x4 acc[8];
#pragma unroll
  for (int nt = 0; nt < 8; nt++) acc[nt] = (f32x4){0.f, 0.f, 0.f, 0.f};

#pragma unroll
  for (int ks = 0; ks < 4; ks++) {
    short8 a = *reinterpret_cast<const short8*>(aph + ks * 32);
#pragma unroll
    for (int nt = 0; nt < 8; nt++) {
      short8 bf = *reinterpret_cast<const short8*>(bself + (size_t)nt * 16 * DIM_C + ks * 32);
      acc[nt] = __builtin_amdgcn_mfma_f32_16x16x32_bf16(a, bf, acc[nt], 0, 0, 0);
    }
  }
#pragma unroll
  for (int ks = 0; ks < 4; ks++) {
    short8 a = *reinterpret_cast<const short8*>(&Al[w * 16 + am][ks * 32 + q * 8]);
#pragma unroll
    for (int nt = 0; nt < 8; nt++) {
      short8 bf = *reinterpret_cast<const short8*>(bneigh + (size_t)nt * 16 * DIM_C + ks * 32);
      acc[nt] = __builtin_amdgcn_mfma_f32_16x16x32_bf16(a, bf, acc[nt], 0, 0, 0);
    }
  }

#pragma unroll
  for (int nt = 0; nt < 8; nt++) {
    int col = nt * 16 + am;
    float bv = bias_l[col];
#pragma unroll
    for (int rr = 0; rr < 4; rr++) {
      int row = n0 + w * 16 + q * 4 + rr;
      if (row < N_NODES_C) {
        float v = acc[nt][rr] + bv;
        out[(size_t)row * DIM_C + col] = fmaxf(v, 0.f);
      }
    }
  }
}

// --------------------------------------------------------------------------
extern "C" void kernel_launch(void* const* d_in, const int* in_sizes, int n_in,
                              void* d_out, int out_size, void* d_ws, size_t ws_size,
                              hipStream_t stream) {
  const float* h      = (const float*)d_in[0];
  const int*   src    = (const int*)d_in[1];
  const int*   dst    = (const int*)d_in[2];
  const float* Wself  = (const float*)d_in[4];
  const float* Wneigh = (const float*)d_in[5];
  const float* bias   = (const float*)d_in[6];
  float*       out    = (float*)d_out;

  char* ws = (char*)d_ws;
  ushort*        hb     = (ushort*)(ws + OFF_HB);
  unsigned*      packed = (unsigned*)(ws + OFF_PK);
  int*           gcur   = (int*)(ws + OFF_GC);
  ushort*        wb     = (ushort*)(ws + OFF_WB);
  unsigned char* h8     = (unsigned char*)(ws + OFF_H8);

  // Zero the 196 bucket cursors only (784 B); all else fully overwritten.
  hipMemsetAsync(gcur, 0, NBKT * sizeof(int), stream);

  sage_cast_bucket<<<NB_SCAT + NB_WCAST + NB_CASTK, 1024, 0, stream>>>(
      h, hb, h8, Wself, Wneigh, wb, src, dst, gcur, packed);
  sage_gather_gemm<<<NBKT * SUBS, 256, 0, stream>>>(packed, gcur, h8, hb, wb,
                                                    bias, out);
}

// Round 2
// 133.353 us; speedup vs baseline: 1.0851x; 1.0851x over previous
//
#include <hip/hip_runtime.h>

// GraphSAGE layer: out = relu(h @ Ws^T + (scatter_mean(h,src,dst)) @ Wn^T + b)
// N=50000, E=800000, dim 128.
// R15: revert R14 fusion (FAILED: grid-limited 12 waves/CU serialized GEMM
//      behind gather; 127->145us). Back to R13 3-kernel structure, then
//      raise gather MLP: SUBS 4->8 (1568 blocks => ~24 waves/CU, was ~12)
//      and edge-unroll 4->8 (8 outstanding uint4 loads/lane). Outstanding
//      loads/CU ~48 -> ~192; gather is latency-bound per R12/R13 evidence.
constexpr int N_NODES_C = 50000;
constexpr int N_EDGES_C = 800000;
constexpr int DIM_C     = 128;

constexpr int NBKT  = 196;    // (50000+255)>>8
constexpr int CAP   = 8192;   // bucket capacity; mean fill 4096, sd ~64
constexpr int EPB_S = 8192;   // edges per scatter block
constexpr int NB_SCAT  = 98;  // (800000+8191)/8192
constexpr int NB_WCAST = 2;   // W-cast blocks: one per matrix
constexpr int NB_CASTK = 391; // h-cast blocks: 1024 thr x 16 elems, guarded

constexpr int SUBS    = 8;    // csr_gather sub-blocks per bucket (R15: was 4)
constexpr int NSUB    = 32;   // nodes per sub-block (R15: was 64)
constexpr int CAP_SUB = 1024; // sub-block edge capacity; mean 512, sd ~23

typedef __attribute__((ext_vector_type(8))) short short8;  // 8 bf16, 4 VGPRs
typedef __attribute__((ext_vector_type(4))) float f32x4;
typedef __attribute__((ext_vector_type(2))) float f32x2;

// Workspace layout (bytes), ~38.7 MB used:
constexpr size_t OFF_HB   = 0;                                   // ushort[N][128]
constexpr size_t OFF_ACC  = (size_t)N_NODES_C * DIM_C * 2;       // 12,800,000
constexpr size_t OFF_PK   = OFF_ACC + (size_t)N_NODES_C * DIM_C * 2;  // 25,600,000
constexpr size_t OFF_GC   = OFF_PK + (size_t)NBKT * CAP * 4;     // 32,022,528
constexpr size_t OFF_WB   = OFF_GC + 1024;                       // ushort[2][128][128]
constexpr size_t OFF_H8   = OFF_WB + 2 * DIM_C * DIM_C * 2;      // uchar[N][128] fp8

// round-to-nearest-even f32 -> bf16 bits (finite inputs only)
static __device__ __forceinline__ ushort f2bf(float f) {
  unsigned u = __float_as_uint(f);
  return (ushort)((u + 0x7FFFu + ((u >> 16) & 1u)) >> 16);
}
static __device__ __forceinline__ unsigned pack2(float a, float b) {
  return (unsigned)f2bf(a) | ((unsigned)f2bf(b) << 16);
}
// 4 floats -> 4 packed OCP e4m3 bytes (HW cvt, RNE)
static __device__ __forceinline__ unsigned pk_fp8x4(float4 a) {
  unsigned u = __builtin_amdgcn_cvt_pk_fp8_f32(a.x, a.y, 0u, false);
  return __builtin_amdgcn_cvt_pk_fp8_f32(a.z, a.w, u, true);
}

// --------------------------------------------------------------------------
// K_A: fused bucket scatter + cast(W) + cast(h -> bf16 AND fp8).
// Scatter block (8192 edges): LDS hist over 196 buckets -> wave-0 scan ->
// one global atomicAdd per nonzero bin (bulk reserve, ~19k total) -> LDS
// counting sort -> per-run coalesced burst write-out.
// --------------------------------------------------------------------------
__global__ __launch_bounds__(1024) void sage_cast_bucket(
    const float* __restrict__ h, ushort* __restrict__ hb,
    unsigned char* __restrict__ h8,
    const float* __restrict__ Wself, const float* __restrict__ Wneigh,
    ushort* __restrict__ wb,
    const int* __restrict__ src, const int* __restrict__ dst,
    int* __restrict__ gcur, unsigned* __restrict__ packed)
{
  const int b = blockIdx.x;
  const int t = threadIdx.x;
  if (b >= NB_SCAT) {
    if (b < NB_SCAT + NB_WCAST) {
      int m = b - NB_SCAT;                    // 0: Wself, 1: Wneigh
      const float* sp = m ? Wneigh : Wself;
      ushort* dp = wb + (size_t)m * DIM_C * DIM_C;
      size_t i = (size_t)t * 16;              // 1024*16 = 16384 exactly
      float4 a0 = *reinterpret_cast<const float4*>(sp + i);
      float4 a1 = *reinterpret_cast<const float4*>(sp + i + 4);
      float4 a2 = *reinterpret_cast<const float4*>(sp + i + 8);
      float4 a3 = *reinterpret_cast<const float4*>(sp + i + 12);
      uint4 o0, o1;
      o0.x = pack2(a0.x, a0.y); o0.y = pack2(a0.z, a0.w);
      o0.z = pack2(a1.x, a1.y); o0.w = pack2(a1.z, a1.w);
      o1.x = pack2(a2.x, a2.y); o1.y = pack2(a2.z, a2.w);
      o1.z = pack2(a3.x, a3.y); o1.w = pack2(a3.z, a3.w);
      *reinterpret_cast<uint4*>(dp + i)     = o0;
      *reinterpret_cast<uint4*>(dp + i + 8) = o1;
    } else {
      int tid = (b - NB_SCAT - NB_WCAST) * 1024 + t;
      if (tid >= 400000) return;              // 400000*16 = 6.4M elems
      size_t i = (size_t)tid * 16;
      float4 a0 = *reinterpret_cast<const float4*>(h + i);
      float4 a1 = *reinterpret_cast<const float4*>(h + i + 4);
      float4 a2 = *reinterpret_cast<const float4*>(h + i + 8);
      float4 a3 = *reinterpret_cast<const float4*>(h + i + 12);
      uint4 o0, o1;
      o0.x = pack2(a0.x, a0.y); o0.y = pack2(a0.z, a0.w);
      o0.z = pack2(a1.x, a1.y); o0.w = pack2(a1.z, a1.w);
      o1.x = pack2(a2.x, a2.y); o1.y = pack2(a2.z, a2.w);
      o1.z = pack2(a3.x, a3.y); o1.w = pack2(a3.z, a3.w);
      *reinterpret_cast<uint4*>(hb + i)     = o0;
      *reinterpret_cast<uint4*>(hb + i + 8) = o1;
      uint4 q;                                 // 16 fp8 bytes
      q.x = pk_fp8x4(a0); q.y = pk_fp8x4(a1);
      q.z = pk_fp8x4(a2); q.w = pk_fp8x4(a3);
      *reinterpret_cast<uint4*>(h8 + i) = q;
    }
    return;
  }

  __shared__ int      bh[256];       // per-bucket count (padded for scan)
  __shared__ int      excl[256];
  __shared__ int      curb[NBKT];
  __shared__ int      bofsG[NBKT];   // reserved base within bucket region
  __shared__ unsigned sorted[EPB_S]; // 32 KB

  const int e0 = b * EPB_S + t * 8;
  const bool l0 = (e0     < N_EDGES_C);      // E%4==0: int4 valid when base<E
  const bool l1 = (e0 + 4 < N_EDGES_C);

  if (t < 256) bh[t] = 0;
  __syncthreads();

  int4 da, db, sa, sb;
  if (l0) {
    da = *reinterpret_cast<const int4*>(dst + e0);
    sa = *reinterpret_cast<const int4*>(src + e0);
    atomicAdd(&bh[da.x >> 8], 1); atomicAdd(&bh[da.y >> 8], 1);
    atomicAdd(&bh[da.z >> 8], 1); atomicAdd(&bh[da.w >> 8], 1);
  }
  if (l1) {
    db = *reinterpret_cast<const int4*>(dst + e0 + 4);
    sb = *reinterpret_cast<const int4*>(src + e0 + 4);
    atomicAdd(&bh[db.x >> 8], 1); atomicAdd(&bh[db.y >> 8], 1);
    atomicAdd(&bh[db.z >> 8], 1); atomicAdd(&bh[db.w >> 8], 1);
  }
  __syncthreads();

  // exclusive scan of bh[256] by wave 0 (4 bins/lane)
  if (t < 64) {
    int base = t * 4;
    int h0 = bh[base], h1 = bh[base + 1], h2 = bh[base + 2], h3 = bh[base + 3];
    int s = h0 + h1 + h2 + h3;
    int x = s;
#pragma unroll
    for (int d = 1; d < 64; d <<= 1) {
      int y = __shfl_up(x, d, 64);
      if (t >= d) x += y;
    }
    int ex = x - s;
    excl[base]     = ex;
    excl[base + 1] = ex + h0;
    excl[base + 2] = ex + h0 + h1;
    excl[base + 3] = ex + h0 + h1 + h2;
  }
  __syncthreads();

  if (t < NBKT) {
    curb[t]  = excl[t];
    bofsG[t] = (bh[t] > 0) ? atomicAdd(&gcur[t], bh[t]) : 0;
  }
  __syncthreads();

#define PLACE(dd, ss)                                            \
  do {                                                           \
    int p_ = atomicAdd(&curb[(dd) >> 8], 1);                     \
    sorted[p_] = ((unsigned)((dd) & 255) << 16) | (unsigned)(ss);\
  } while (0)
  if (l0) { PLACE(da.x, sa.x); PLACE(da.y, sa.y); PLACE(da.z, sa.z); PLACE(da.w, sa.w); }
  if (l1) { PLACE(db.x, sb.x); PLACE(db.y, sb.y); PLACE(db.z, sb.z); PLACE(db.w, sb.w); }
#undef PLACE
  __syncthreads();

  // coalesced burst write-out: wave w owns buckets w, w+16, ...
  const int w    = t >> 6;
  const int lane = t & 63;
  for (int k = w; k < NBKT; k += 16) {
    int len = bh[k];
    int gb  = bofsG[k];
    if (gb + len > CAP) len = CAP - gb;      // statistically unreachable
    int lb  = excl[k];
    unsigned* outp = packed + (size_t)k * CAP + gb;
    for (int off = lane; off < len; off += 64)
      outp[off] = sorted[lb + off];
  }
}

// --------------------------------------------------------------------------
// K_B: per-sub-bucket counting sort + gather-mean, fp8 rows (128B/row).
// Block (bucket b, sub s) owns node-ids rid in [s*32, s*32+32). 1568x256.
// R15: SUBS=8 doubles grid (=> ~24 waves/CU) and edge loop unrolled x8
// (8 outstanding 16B loads/lane). Gather is one round: 32 nodes x 8 lanes.
// 1/deg from hist (== input deg by construction).
// --------------------------------------------------------------------------
__global__ __launch_bounds__(256) void sage_csr_gather(
    const unsigned* __restrict__ packed, const int* __restrict__ gcur,
    const unsigned char* __restrict__ h8, ushort* __restrict__ accb)
{
  __shared__ int    hist[NSUB];
  __shared__ int    excl_s[NSUB];
  __shared__ int    curb[NSUB];
  __shared__ ushort esrc_l[CAP_SUB];   // 2 KB

  const int b   = blockIdx.x >> 3;     // bucket
  const int sub = blockIdx.x & 7;
  const int rlo = sub * NSUB;
  const int t = threadIdx.x;
  const int count = min(gcur[b], CAP);
  const unsigned* pk = packed + (size_t)b * CAP;
  const int nvec = count >> 2;
  const int ntail = count & 3;

  if (t < NSUB) hist[t] = 0;
  __syncthreads();

  // pass 1: histogram of our rid range (vectorized scan, L2-hot)
  for (int g = t; g < nvec; g += 256) {
    uint4 w4 = *reinterpret_cast<const uint4*>(pk + g * 4);
    int r;
    r = (int)(w4.x >> 16) - rlo; if ((unsigned)r < (unsigned)NSUB) atomicAdd(&hist[r], 1);
    r = (int)(w4.y >> 16) - rlo; if ((unsigned)r < (unsigned)NSUB) atomicAdd(&hist[r], 1);
    r = (int)(w4.z >> 16) - rlo; if ((unsigned)r < (unsigned)NSUB) atomicAdd(&hist[r], 1);
    r = (int)(w4.w >> 16) - rlo; if ((unsigned)r < (unsigned)NSUB) atomicAdd(&hist[r], 1);
  }
  if (t < ntail) {
    int r = (int)(pk[nvec * 4 + t] >> 16) - rlo;
    if ((unsigned)r < (unsigned)NSUB) atomicAdd(&hist[r], 1);
  }
  __syncthreads();

  // exclusive scan of hist[32] by lanes 0..31 of wave 0
  if (t < NSUB) {
    int v = hist[t];
    int x = v;
#pragma unroll
    for (int d = 1; d < NSUB; d <<= 1) {
      int y = __shfl_up(x, d, 64);
      if (t >= d) x += y;
    }
    excl_s[t] = x - v;
    curb[t]   = x - v;
  }
  __syncthreads();

  // pass 2: filtered placement
  for (int g = t; g < nvec; g += 256) {
    uint4 w4 = *reinterpret_cast<const uint4*>(pk + g * 4);
    unsigned ww[4] = {w4.x, w4.y, w4.z, w4.w};
#pragma unroll
    for (int j = 0; j < 4; j++) {
      int r = (int)(ww[j] >> 16) - rlo;
      if ((unsigned)r < (unsigned)NSUB) {
        int p = atomicAdd(&curb[r], 1);
        esrc_l[p] = (ushort)(ww[j] & 0xFFFFu);
      }
    }
  }
  if (t < ntail) {
    unsigned wv = pk[nvec * 4 + t];
    int r = (int)(wv >> 16) - rlo;
    if ((unsigned)r < (unsigned)NSUB) {
      int p = atomicAdd(&curb[r], 1);
      esrc_l[p] = (ushort)(wv & 0xFFFFu);
    }
  }
  __syncthreads();

  // gather: 32 nodes x 8 lanes/node, 16 fp8 per lane (uint4), unroll x8.
  const int c  = (t & 7) << 4;
  const int lr = t >> 3;             // local rid 0..31
  const int n  = (b << 8) + rlo + lr;
  if (n >= N_NODES_C) return;
  const int begin = excl_s[lr];
  const int cnt   = hist[lr];
  const int end   = begin + cnt;

  float s[16];
#pragma unroll
  for (int j = 0; j < 16; j++) s[j] = 0.f;

#define ACCD(wd, o)                                                \
  do {                                                             \
    f32x2 p_;                                                      \
    p_ = __builtin_amdgcn_cvt_pk_f32_fp8((wd), false);             \
    s[(o)]     += p_.x; s[(o) + 1] += p_.y;                        \
    p_ = __builtin_amdgcn_cvt_pk_f32_fp8((wd), true);              \
    s[(o) + 2] += p_.x; s[(o) + 3] += p_.y;                        \
  } while (0)
#define ACC16(u)                                                   \
  do { ACCD((u).x, 0); ACCD((u).y, 4); ACCD((u).z, 8); ACCD((u).w, 12); } while (0)

  int i = begin;
  for (; i + 7 < end; i += 8) {
    int e0 = esrc_l[i],     e1 = esrc_l[i + 1], e2 = esrc_l[i + 2], e3 = esrc_l[i + 3];
    int e4 = esrc_l[i + 4], e5 = esrc_l[i + 5], e6 = esrc_l[i + 6], e7 = esrc_l[i + 7];
    uint4 a0 = *reinterpret_cast<const uint4*>(h8 + (size_t)e0 * DIM_C + c);
    uint4 a1 = *reinterpret_cast<const uint4*>(h8 + (size_t)e1 * DIM_C + c);
    uint4 a2 = *reinterpret_cast<const uint4*>(h8 + (size_t)e2 * DIM_C + c);
    uint4 a3 = *reinterpret_cast<const uint4*>(h8 + (size_t)e3 * DIM_C + c);
    uint4 a4 = *reinterpret_cast<const uint4*>(h8 + (size_t)e4 * DIM_C + c);
    uint4 a5 = *reinterpret_cast<const uint4*>(h8 + (size_t)e5 * DIM_C + c);
    uint4 a6 = *reinterpret_cast<const uint4*>(h8 + (size_t)e6 * DIM_C + c);
    uint4 a7 = *reinterpret_cast<const uint4*>(h8 + (size_t)e7 * DIM_C + c);
    ACC16(a0); ACC16(a1); ACC16(a2); ACC16(a3);
    ACC16(a4); ACC16(a5); ACC16(a6); ACC16(a7);
  }
  for (; i + 3 < end; i += 4) {
    int e0 = esrc_l[i], e1 = esrc_l[i + 1], e2 = esrc_l[i + 2], e3 = esrc_l[i + 3];
    uint4 a0 = *reinterpret_cast<const uint4*>(h8 + (size_t)e0 * DIM_C + c);
    uint4 a1 = *reinterpret_cast<const uint4*>(h8 + (size_t)e1 * DIM_C + c);
    uint4 a2 = *reinterpret_cast<const uint4*>(h8 + (size_t)e2 * DIM_C + c);
    uint4 a3 = *reinterpret_cast<const uint4*>(h8 + (size_t)e3 * DIM_C + c);
    ACC16(a0); ACC16(a1); ACC16(a2); ACC16(a3);
  }
  for (; i < end; i++) {
    int e0 = esrc_l[i];
    uint4 a0 = *reinterpret_cast<const uint4*>(h8 + (size_t)e0 * DIM_C + c);
    ACC16(a0);
  }
#undef ACC16
#undef ACCD

  float id = 1.0f / (float)max(cnt, 1);   // == 1/deg[n] by construction
  uint4 o0, o1;
  o0.x = pack2(s[0]  * id, s[1]  * id);
  o0.y = pack2(s[2]  * id, s[3]  * id);
  o0.z = pack2(s[4]  * id, s[5]  * id);
  o0.w = pack2(s[6]  * id, s[7]  * id);
  o1.x = pack2(s[8]  * id, s[9]  * id);
  o1.y = pack2(s[10] * id, s[11] * id);
  o1.z = pack2(s[12] * id, s[13] * id);
  o1.w = pack2(s[14] * id, s[15] * id);
  *reinterpret_cast<uint4*>(accb + (size_t)n * DIM_C + c)     = o0;
  *reinterpret_cast<uint4*>(accb + (size_t)n * DIM_C + c + 8) = o1;
}

// --------------------------------------------------------------------------
// K4: fused bf16 MFMA GEMM, K=256 (k<128 from h_bf16, k>=128 from acc_bf16).
// Block = 256 thr (4 waves), 128 rows/block. W staged from pre-cast bf16
// global into padded LDS (uint4 copies).
// Layouts (m89/m91-verified): A[m=lane&15][k=quad*8+j];
// B from W[n][k] with n=lane&15, k=quad*8+j; C/D col=lane&15, row=quad*4+reg.
// --------------------------------------------------------------------------
__global__ __launch_bounds__(256) void sage_gemm_mfma(
    const ushort* __restrict__ hb, const ushort* __restrict__ accb,
    const ushort* __restrict__ wb, const float* __restrict__ bias,
    float* __restrict__ out)
{
  __shared__ ushort Bl[DIM_C][256 + 8];   // 67,584 B
  __shared__ float  bias_l[DIM_C];

  const int t = threadIdx.x;

  for (int idx = t; idx < DIM_C * 16; idx += 256) {
    int n  = idx >> 4;
    int c8 = (idx & 15) << 3;
    uint4 w0 = *reinterpret_cast<const uint4*>(wb + (size_t)n * DIM_C + c8);
    uint4 w1 = *reinterpret_cast<const uint4*>(wb + (size_t)(DIM_C + n) * DIM_C + c8);
    *reinterpret_cast<uint4*>(&Bl[n][c8])       = w0;
    *reinterpret_cast<uint4*>(&Bl[n][128 + c8]) = w1;
  }
  if (t < DIM_C) bias_l[t] = bias[t];
  __syncthreads();

  const int lane = t & 63;
  const int w    = t >> 6;
  const int am   = lane & 15;
  const int q    = lane >> 4;
  const int mb   = blockIdx.x * 128;
  const int m0   = mb + w * 16;        // row-tile 0
  const int m1   = mb + 64 + w * 16;   // row-tile 1

  int r0 = m0 + am; if (r0 >= N_NODES_C) r0 = N_NODES_C - 1;
  int r1 = m1 + am; if (r1 >= N_NODES_C) r1 = N_NODES_C - 1;
  const ushort* aph0 = hb   + (size_t)r0 * DIM_C + q * 8;
  const ushort* apa0 = accb + (size_t)r0 * DIM_C + q * 8;
  const ushort* aph1 = hb   + (size_t)r1 * DIM_C + q * 8;
  const ushort* apa1 = accb + (size_t)r1 * DIM_C + q * 8;

  f32x4 acc[2][8];
#pragma unroll
  for (int i = 0; i < 2; i++)
#pragma unroll
    for (int nt = 0; nt < 8; nt++) acc[i][nt] = (f32x4){0.f, 0.f, 0.f, 0.f};

#pragma unroll
  for (int ks = 0; ks < 4; ks++) {
    short8 a0 = *reinterpret_cast<const short8*>(aph0 + ks * 32);
    short8 a1 = *reinterpret_cast<const short8*>(aph1 + ks * 32);
#pragma unroll
    for (int nt = 0; nt < 8; nt++) {
      short8 bf = *reinterpret_cast<const short8*>(&Bl[nt * 16 + am][ks * 32 + q * 8]);
      acc[0][nt] = __builtin_amdgcn_mfma_f32_16x16x32_bf16(a0, bf, acc[0][nt], 0, 0, 0);
      acc[1][nt] = __builtin_amdgcn_mfma_f32_16x16x32_bf16(a1, bf, acc[1][nt], 0, 0, 0);
    }
  }
#pragma unroll
  for (int ks = 0; ks < 4; ks++) {
    short8 a0 = *reinterpret_cast<const short8*>(apa0 + ks * 32);
    short8 a1 = *reinterpret_cast<const short8*>(apa1 + ks * 32);
#pragma unroll
    for (int nt = 0; nt < 8; nt++) {
      short8 bf = *reinterpret_cast<const short8*>(&Bl[nt * 16 + am][128 + ks * 32 + q * 8]);
      acc[0][nt] = __builtin_amdgcn_mfma_f32_16x16x32_bf16(a0, bf, acc[0][nt], 0, 0, 0);
      acc[1][nt] = __builtin_amdgcn_mfma_f32_16x16x32_bf16(a1, bf, acc[1][nt], 0, 0, 0);
    }
  }

#pragma unroll
  for (int i = 0; i < 2; i++) {
    int mt = (i == 0) ? m0 : m1;
#pragma unroll
    for (int nt = 0; nt < 8; nt++) {
      int col = nt * 16 + am;
      float bv = bias_l[col];
#pragma unroll
      for (int rr = 0; rr < 4; rr++) {
        int row = mt + q * 4 + rr;
        if (row < N_NODES_C) {
          float v = acc[i][nt][rr] + bv;
          out[(size_t)row * DIM_C + col] = fmaxf(v, 0.f);
        }
      }
    }
  }
}

// --------------------------------------------------------------------------
extern "C" void kernel_launch(void* const* d_in, const int* in_sizes, int n_in,
                              void* d_out, int out_size, void* d_ws, size_t ws_size,
                              hipStream_t stream) {
  const float* h      = (const float*)d_in[0];
  const int*   src    = (const int*)d_in[1];
  const int*   dst    = (const int*)d_in[2];
  const float* Wself  = (const float*)d_in[4];
  const float* Wneigh = (const float*)d_in[5];
  const float* bias   = (const float*)d_in[6];
  float*       out    = (float*)d_out;

  char* ws = (char*)d_ws;
  ushort*        hb     = (ushort*)(ws + OFF_HB);
  ushort*        accb   = (ushort*)(ws + OFF_ACC);
  unsigned*      packed = (unsigned*)(ws + OFF_PK);
  int*           gcur   = (int*)(ws + OFF_GC);
  ushort*        wb     = (ushort*)(ws + OFF_WB);
  unsigned char* h8     = (unsigned char*)(ws + OFF_H8);

  // Zero the 196 bucket cursors only (784 B); all else fully overwritten.
  hipMemsetAsync(gcur, 0, NBKT * sizeof(int), stream);

  sage_cast_bucket<<<NB_SCAT + NB_WCAST + NB_CASTK, 1024, 0, stream>>>(
      h, hb, h8, Wself, Wneigh, wb, src, dst, gcur, packed);
  sage_csr_gather <<<NBKT * SUBS, 256, 0, stream>>>(packed, gcur, h8, accb);
  sage_gemm_mfma  <<<(N_NODES_C + 127) / 128, 256, 0, stream>>>(hb, accb, wb,
                                                                bias, out);
}

// Round 3
// 129.837 us; speedup vs baseline: 1.1145x; 1.0271x over previous
//
#include <hip/hip_runtime.h>

// GraphSAGE layer: out = relu(h @ Ws^T + (scatter_mean(h,src,dst)) @ Wn^T + b)
// N=50000, E=800000, dim 128.
// R16: fine-grained bucketing. R15 showed sub-block re-scan+filter of the
//      4096-edge bucket dominates (SUBS=8 doubled it and REGRESSED 127->133).
//      K_A now counting-sorts into 1568 bins of 32 nodes (dst>>5); each K_B
//      block owns one bin and scans only its own ~512 edges (8x less scan
//      than R13, no filter predicates), while keeping the 1568-block grid
//      (~24 waves/CU) and unroll-8 gather from R15.
constexpr int N_NODES_C = 50000;
constexpr int N_EDGES_C = 800000;
constexpr int DIM_C     = 128;

constexpr int NBKT  = 1568;   // (50000+31)>>5, 32 nodes per bin
constexpr int NBPAD = 2048;   // padded bin count for 64x32 wave scan
constexpr int CAP   = 1024;   // bin capacity; mean fill 512, sd ~23
constexpr int EPB_S = 8192;   // edges per scatter block
constexpr int NB_SCAT  = 98;  // (800000+8191)/8192
constexpr int NB_WCAST = 2;   // W-cast blocks: one per matrix
constexpr int NB_CASTK = 391; // h-cast blocks: 1024 thr x 16 elems, guarded

constexpr int NSUB    = 32;   // nodes per bin / K_B block

typedef __attribute__((ext_vector_type(8))) short short8;  // 8 bf16, 4 VGPRs
typedef __attribute__((ext_vector_type(4))) float f32x4;
typedef __attribute__((ext_vector_type(2))) float f32x2;

// Workspace layout (bytes), ~38.5 MB used:
constexpr size_t OFF_HB   = 0;                                   // ushort[N][128]
constexpr size_t OFF_ACC  = (size_t)N_NODES_C * DIM_C * 2;       // 12,800,000
constexpr size_t OFF_PK   = OFF_ACC + (size_t)N_NODES_C * DIM_C * 2;  // 25,600,000
constexpr size_t OFF_GC   = OFF_PK + (size_t)NBKT * CAP * 4;     // 32,022,528
constexpr size_t OFF_WB   = OFF_GC + 8192;                       // ushort[2][128][128]
constexpr size_t OFF_H8   = OFF_WB + 2 * DIM_C * DIM_C * 2;      // uchar[N][128] fp8

// round-to-nearest-even f32 -> bf16 bits (finite inputs only)
static __device__ __forceinline__ ushort f2bf(float f) {
  unsigned u = __float_as_uint(f);
  return (ushort)((u + 0x7FFFu + ((u >> 16) & 1u)) >> 16);
}
static __device__ __forceinline__ unsigned pack2(float a, float b) {
  return (unsigned)f2bf(a) | ((unsigned)f2bf(b) << 16);
}
// 4 floats -> 4 packed OCP e4m3 bytes (HW cvt, RNE)
static __device__ __forceinline__ unsigned pk_fp8x4(float4 a) {
  unsigned u = __builtin_amdgcn_cvt_pk_fp8_f32(a.x, a.y, 0u, false);
  return __builtin_amdgcn_cvt_pk_fp8_f32(a.z, a.w, u, true);
}

// --------------------------------------------------------------------------
// K_A: fused bucket scatter + cast(W) + cast(h -> bf16 AND fp8).
// Scatter block (8192 edges): LDS hist over 1568 fine bins (32 nodes each)
// -> wave-0 scan (32 bins/lane) -> one global atomicAdd per nonzero bin ->
// LDS counting sort -> write-out, 4 bins per wave (16 lanes each).
// LDS: 8K + 8K + 6.3K + 6.3K + 32K = 61.7 KB.
// --------------------------------------------------------------------------
__global__ __launch_bounds__(1024) void sage_cast_bucket(
    const float* __restrict__ h, ushort* __restrict__ hb,
    unsigned char* __restrict__ h8,
    const float* __restrict__ Wself, const float* __restrict__ Wneigh,
    ushort* __restrict__ wb,
    const int* __restrict__ src, const int* __restrict__ dst,
    int* __restrict__ gcur, unsigned* __restrict__ packed)
{
  const int b = blockIdx.x;
  const int t = threadIdx.x;
  if (b >= NB_SCAT) {
    if (b < NB_SCAT + NB_WCAST) {
      int m = b - NB_SCAT;                    // 0: Wself, 1: Wneigh
      const float* sp = m ? Wneigh : Wself;
      ushort* dp = wb + (size_t)m * DIM_C * DIM_C;
      size_t i = (size_t)t * 16;              // 1024*16 = 16384 exactly
      float4 a0 = *reinterpret_cast<const float4*>(sp + i);
      float4 a1 = *reinterpret_cast<const float4*>(sp + i + 4);
      float4 a2 = *reinterpret_cast<const float4*>(sp + i + 8);
      float4 a3 = *reinterpret_cast<const float4*>(sp + i + 12);
      uint4 o0, o1;
      o0.x = pack2(a0.x, a0.y); o0.y = pack2(a0.z, a0.w);
      o0.z = pack2(a1.x, a1.y); o0.w = pack2(a1.z, a1.w);
      o1.x = pack2(a2.x, a2.y); o1.y = pack2(a2.z, a2.w);
      o1.z = pack2(a3.x, a3.y); o1.w = pack2(a3.z, a3.w);
      *reinterpret_cast<uint4*>(dp + i)     = o0;
      *reinterpret_cast<uint4*>(dp + i + 8) = o1;
    } else {
      int tid = (b - NB_SCAT - NB_WCAST) * 1024 + t;
      if (tid >= 400000) return;              // 400000*16 = 6.4M elems
      size_t i = (size_t)tid * 16;
      float4 a0 = *reinterpret_cast<const float4*>(h + i);
      float4 a1 = *reinterpret_cast<const float4*>(h + i + 4);
      float4 a2 = *reinterpret_cast<const float4*>(h + i + 8);
      float4 a3 = *reinterpret_cast<const float4*>(h + i + 12);
      uint4 o0, o1;
      o0.x = pack2(a0.x, a0.y); o0.y = pack2(a0.z, a0.w);
      o0.z = pack2(a1.x, a1.y); o0.w = pack2(a1.z, a1.w);
      o1.x = pack2(a2.x, a2.y); o1.y = pack2(a2.z, a2.w);
      o1.z = pack2(a3.x, a3.y); o1.w = pack2(a3.z, a3.w);
      *reinterpret_cast<uint4*>(hb + i)     = o0;
      *reinterpret_cast<uint4*>(hb + i + 8) = o1;
      uint4 q;                                 // 16 fp8 bytes
      q.x = pk_fp8x4(a0); q.y = pk_fp8x4(a1);
      q.z = pk_fp8x4(a2); q.w = pk_fp8x4(a3);
      *reinterpret_cast<uint4*>(h8 + i) = q;
    }
    return;
  }

  __shared__ int      bh[NBPAD];     // per-bin count (padded for scan)
  __shared__ int      excl[NBPAD];
  __shared__ int      curb[NBKT];
  __shared__ int      bofsG[NBKT];   // reserved base within bin region
  __shared__ unsigned sorted[EPB_S]; // 32 KB

  const int e0 = b * EPB_S + t * 8;
  const bool l0 = (e0     < N_EDGES_C);      // E%4==0: int4 valid when base<E
  const bool l1 = (e0 + 4 < N_EDGES_C);

  bh[t] = 0; bh[t + 1024] = 0;
  __syncthreads();

  int4 da, db, sa, sb;
  if (l0) {
    da = *reinterpret_cast<const int4*>(dst + e0);
    sa = *reinterpret_cast<const int4*>(src + e0);
    atomicAdd(&bh[da.x >> 5], 1); atomicAdd(&bh[da.y >> 5], 1);
    atomicAdd(&bh[da.z >> 5], 1); atomicAdd(&bh[da.w >> 5], 1);
  }
  if (l1) {
    db = *reinterpret_cast<const int4*>(dst + e0 + 4);
    sb = *reinterpret_cast<const int4*>(src + e0 + 4);
    atomicAdd(&bh[db.x >> 5], 1); atomicAdd(&bh[db.y >> 5], 1);
    atomicAdd(&bh[db.z >> 5], 1); atomicAdd(&bh[db.w >> 5], 1);
  }
  __syncthreads();

  // exclusive scan of bh[2048] by wave 0 (32 bins/lane)
  if (t < 64) {
    int base = t * 32;
    int hs[32];
    int s = 0;
#pragma unroll
    for (int j = 0; j < 32; j++) { hs[j] = bh[base + j]; s += hs[j]; }
    int x = s;
#pragma unroll
    for (int d = 1; d < 64; d <<= 1) {
      int y = __shfl_up(x, d, 64);
      if (t >= d) x += y;
    }
    int ex = x - s;
#pragma unroll
    for (int j = 0; j < 32; j++) { excl[base + j] = ex; ex += hs[j]; }
  }
  __syncthreads();

  // reserve global space per nonzero bin (2 bins per thread)
  {
    int k0 = t, k1 = t + 1024;
    if (k0 < NBKT) { curb[k0] = excl[k0]; bofsG[k0] = (bh[k0] > 0) ? atomicAdd(&gcur[k0], bh[k0]) : 0; }
    if (k1 < NBKT) { curb[k1] = excl[k1]; bofsG[k1] = (bh[k1] > 0) ? atomicAdd(&gcur[k1], bh[k1]) : 0; }
  }
  __syncthreads();

#define PLACE(dd, ss)                                            \
  do {                                                           \
    int p_ = atomicAdd(&curb[(dd) >> 5], 1);                     \
    sorted[p_] = ((unsigned)((dd) & 31) << 16) | (unsigned)(ss); \
  } while (0)
  if (l0) { PLACE(da.x, sa.x); PLACE(da.y, sa.y); PLACE(da.z, sa.z); PLACE(da.w, sa.w); }
  if (l1) { PLACE(db.x, sb.x); PLACE(db.y, sb.y); PLACE(db.z, sb.z); PLACE(db.w, sb.w); }
#undef PLACE
  __syncthreads();

  // write-out: 4 bins per wave, 16 lanes per bin (mean run ~5)
  const int w    = t >> 6;
  const int lane = t & 63;
  const int sbk  = lane >> 4;          // 0..3: which of the wave's 4 bins
  const int sl   = lane & 15;
  for (int k = w * 4 + sbk; k < NBKT; k += 64) {
    int len = bh[k];
    if (len == 0) continue;
    int gb  = bofsG[k];
    if (gb + len > CAP) len = CAP - gb;      // statistically unreachable
    int lb  = excl[k];
    unsigned* outp = packed + (size_t)k * CAP + gb;
    for (int off = sl; off < len; off += 16)
      outp[off] = sorted[lb + off];
  }
}

// --------------------------------------------------------------------------
// K_B: per-bin counting sort + gather-mean, fp8 rows (128B/row).
// Block = bin = 32 nodes. 1568 x 256 thr (~24 waves/CU). All edges in the
// bin belong to this block: no filtering, scan is 2 passes x ~512 edges.
// Gather: 32 nodes x 8 lanes/node, 16 fp8/lane (uint4), unroll x8.
// 1/deg from hist (== input deg by construction).
// --------------------------------------------------------------------------
__global__ __launch_bounds__(256) void sage_csr_gather(
    const unsigned* __restrict__ packed, const int* __restrict__ gcur,
    const unsigned char* __restrict__ h8, ushort* __restrict__ accb)
{
  __shared__ int    hist[NSUB];
  __shared__ int    excl_s[NSUB];
  __shared__ int    curb[NSUB];
  __shared__ ushort esrc_l[CAP];       // 2 KB

  const int b = blockIdx.x;
  const int t = threadIdx.x;
  const int count = min(gcur[b], CAP);
  const unsigned* pk = packed + (size_t)b * CAP;
  const int nvec = count >> 2;
  const int ntail = count & 3;

  if (t < NSUB) hist[t] = 0;
  __syncthreads();

  // pass 1: histogram (bin-local rids in high half-word, no filtering)
  for (int g = t; g < nvec; g += 256) {
    uint4 w4 = *reinterpret_cast<const uint4*>(pk + g * 4);
    atomicAdd(&hist[w4.x >> 16], 1);
    atomicAdd(&hist[w4.y >> 16], 1);
    atomicAdd(&hist[w4.z >> 16], 1);
    atomicAdd(&hist[w4.w >> 16], 1);
  }
  if (t < ntail) atomicAdd(&hist[pk[nvec * 4 + t] >> 16], 1);
  __syncthreads();

  // exclusive scan of hist[32] by lanes 0..31
  if (t < NSUB) {
    int v = hist[t];
    int x = v;
#pragma unroll
    for (int d = 1; d < NSUB; d <<= 1) {
      int y = __shfl_up(x, d, 64);
      if (t >= d) x += y;
    }
    excl_s[t] = x - v;
    curb[t]   = x - v;
  }
  __syncthreads();

  // pass 2: placement
  for (int g = t; g < nvec; g += 256) {
    uint4 w4 = *reinterpret_cast<const uint4*>(pk + g * 4);
    unsigned ww[4] = {w4.x, w4.y, w4.z, w4.w};
#pragma unroll
    for (int j = 0; j < 4; j++) {
      int p = atomicAdd(&curb[ww[j] >> 16], 1);
      esrc_l[p] = (ushort)(ww[j] & 0xFFFFu);
    }
  }
  if (t < ntail) {
    unsigned wv = pk[nvec * 4 + t];
    int p = atomicAdd(&curb[wv >> 16], 1);
    esrc_l[p] = (ushort)(wv & 0xFFFFu);
  }
  __syncthreads();

  // gather: 32 nodes x 8 lanes/node, 16 fp8 per lane (uint4), unroll x8.
  const int c  = (t & 7) << 4;
  const int lr = t >> 3;             // local rid 0..31
  const int n  = (b << 5) + lr;
  if (n >= N_NODES_C) return;
  const int begin = excl_s[lr];
  const int cnt   = hist[lr];
  const int end   = begin + cnt;

  float s[16];
#pragma unroll
  for (int j = 0; j < 16; j++) s[j] = 0.f;

#define ACCD(wd, o)                                                \
  do {                                                             \
    f32x2 p_;                                                      \
    p_ = __builtin_amdgcn_cvt_pk_f32_fp8((wd), false);             \
    s[(o)]     += p_.x; s[(o) + 1] += p_.y;                        \
    p_ = __builtin_amdgcn_cvt_pk_f32_fp8((wd), true);              \
    s[(o) + 2] += p_.x; s[(o) + 3] += p_.y;                        \
  } while (0)
#define ACC16(u)                                                   \
  do { ACCD((u).x, 0); ACCD((u).y, 4); ACCD((u).z, 8); ACCD((u).w, 12); } while (0)

  int i = begin;
  for (; i + 7 < end; i += 8) {
    int e0 = esrc_l[i],     e1 = esrc_l[i + 1], e2 = esrc_l[i + 2], e3 = esrc_l[i + 3];
    int e4 = esrc_l[i + 4], e5 = esrc_l[i + 5], e6 = esrc_l[i + 6], e7 = esrc_l[i + 7];
    uint4 a0 = *reinterpret_cast<const uint4*>(h8 + (size_t)e0 * DIM_C + c);
    uint4 a1 = *reinterpret_cast<const uint4*>(h8 + (size_t)e1 * DIM_C + c);
    uint4 a2 = *reinterpret_cast<const uint4*>(h8 + (size_t)e2 * DIM_C + c);
    uint4 a3 = *reinterpret_cast<const uint4*>(h8 + (size_t)e3 * DIM_C + c);
    uint4 a4 = *reinterpret_cast<const uint4*>(h8 + (size_t)e4 * DIM_C + c);
    uint4 a5 = *reinterpret_cast<const uint4*>(h8 + (size_t)e5 * DIM_C + c);
    uint4 a6 = *reinterpret_cast<const uint4*>(h8 + (size_t)e6 * DIM_C + c);
    uint4 a7 = *reinterpret_cast<const uint4*>(h8 + (size_t)e7 * DIM_C + c);
    ACC16(a0); ACC16(a1); ACC16(a2); ACC16(a3);
    ACC16(a4); ACC16(a5); ACC16(a6); ACC16(a7);
  }
  for (; i + 3 < end; i += 4) {
    int e0 = esrc_l[i], e1 = esrc_l[i + 1], e2 = esrc_l[i + 2], e3 = esrc_l[i + 3];
    uint4 a0 = *reinterpret_cast<const uint4*>(h8 + (size_t)e0 * DIM_C + c);
    uint4 a1 = *reinterpret_cast<const uint4*>(h8 + (size_t)e1 * DIM_C + c);
    uint4 a2 = *reinterpret_cast<const uint4*>(h8 + (size_t)e2 * DIM_C + c);
    uint4 a3 = *reinterpret_cast<const uint4*>(h8 + (size_t)e3 * DIM_C + c);
    ACC16(a0); ACC16(a1); ACC16(a2); ACC16(a3);
  }
  for (; i < end; i++) {
    int e0 = esrc_l[i];
    uint4 a0 = *reinterpret_cast<const uint4*>(h8 + (size_t)e0 * DIM_C + c);
    ACC16(a0);
  }
#undef ACC16
#undef ACCD

  float id = 1.0f / (float)max(cnt, 1);   // == 1/deg[n] by construction
  uint4 o0, o1;
  o0.x = pack2(s[0]  * id, s[1]  * id);
  o0.y = pack2(s[2]  * id, s[3]  * id);
  o0.z = pack2(s[4]  * id, s[5]  * id);
  o0.w = pack2(s[6]  * id, s[7]  * id);
  o1.x = pack2(s[8]  * id, s[9]  * id);
  o1.y = pack2(s[10] * id, s[11] * id);
  o1.z = pack2(s[12] * id, s[13] * id);
  o1.w = pack2(s[14] * id, s[15] * id);
  *reinterpret_cast<uint4*>(accb + (size_t)n * DIM_C + c)     = o0;
  *reinterpret_cast<uint4*>(accb + (size_t)n * DIM_C + c + 8) = o1;
}

// --------------------------------------------------------------------------
// K4: fused bf16 MFMA GEMM, K=256 (k<128 from h_bf16, k>=128 from acc_bf16).
// Block = 256 thr (4 waves), 128 rows/block. W staged from pre-cast bf16
// global into padded LDS (uint4 copies).
// Layouts (m89/m91-verified): A[m=lane&15][k=quad*8+j];
// B from W[n][k] with n=lane&15, k=quad*8+j; C/D col=lane&15, row=quad*4+reg.
// --------------------------------------------------------------------------
__global__ __launch_bounds__(256) void sage_gemm_mfma(
    const ushort* __restrict__ hb, const ushort* __restrict__ accb,
    const ushort* __restrict__ wb, const float* __restrict__ bias,
    float* __restrict__ out)
{
  __shared__ ushort Bl[DIM_C][256 + 8];   // 67,584 B
  __shared__ float  bias_l[DIM_C];

  const int t = threadIdx.x;

  for (int idx = t; idx < DIM_C * 16; idx += 256) {
    int n  = idx >> 4;
    int c8 = (idx & 15) << 3;
    uint4 w0 = *reinterpret_cast<const uint4*>(wb + (size_t)n * DIM_C + c8);
    uint4 w1 = *reinterpret_cast<const uint4*>(wb + (size_t)(DIM_C + n) * DIM_C + c8);
    *reinterpret_cast<uint4*>(&Bl[n][c8])       = w0;
    *reinterpret_cast<uint4*>(&Bl[n][128 + c8]) = w1;
  }
  if (t < DIM_C) bias_l[t] = bias[t];
  __syncthreads();

  const int lane = t & 63;
  const int w    = t >> 6;
  const int am   = lane & 15;
  const int q    = lane >> 4;
  const int mb   = blockIdx.x * 128;
  const int m0   = mb + w * 16;        // row-tile 0
  const int m1   = mb + 64 + w * 16;   // row-tile 1

  int r0 = m0 + am; if (r0 >= N_NODES_C) r0 = N_NODES_C - 1;
  int r1 = m1 + am; if (r1 >= N_NODES_C) r1 = N_NODES_C - 1;
  const ushort* aph0 = hb   + (size_t)r0 * DIM_C + q * 8;
  const ushort* apa0 = accb + (size_t)r0 * DIM_C + q * 8;
  const ushort* aph1 = hb   + (size_t)r1 * DIM_C + q * 8;
  const ushort* apa1 = accb + (size_t)r1 * DIM_C + q * 8;

  f32x4 acc[2][8];
#pragma unroll
  for (int i = 0; i < 2; i++)
#pragma unroll
    for (int nt = 0; nt < 8; nt++) acc[i][nt] = (f32x4){0.f, 0.f, 0.f, 0.f};

#pragma unroll
  for (int ks = 0; ks < 4; ks++) {
    short8 a0 = *reinterpret_cast<const short8*>(aph0 + ks * 32);
    short8 a1 = *reinterpret_cast<const short8*>(aph1 + ks * 32);
#pragma unroll
    for (int nt = 0; nt < 8; nt++) {
      short8 bf = *reinterpret_cast<const short8*>(&Bl[nt * 16 + am][ks * 32 + q * 8]);
      acc[0][nt] = __builtin_amdgcn_mfma_f32_16x16x32_bf16(a0, bf, acc[0][nt], 0, 0, 0);
      acc[1][nt] = __builtin_amdgcn_mfma_f32_16x16x32_bf16(a1, bf, acc[1][nt], 0, 0, 0);
    }
  }
#pragma unroll
  for (int ks = 0; ks < 4; ks++) {
    short8 a0 = *reinterpret_cast<const short8*>(apa0 + ks * 32);
    short8 a1 = *reinterpret_cast<const short8*>(apa1 + ks * 32);
#pragma unroll
    for (int nt = 0; nt < 8; nt++) {
      short8 bf = *reinterpret_cast<const short8*>(&Bl[nt * 16 + am][128 + ks * 32 + q * 8]);
      acc[0][nt] = __builtin_amdgcn_mfma_f32_16x16x32_bf16(a0, bf, acc[0][nt], 0, 0, 0);
      acc[1][nt] = __builtin_amdgcn_mfma_f32_16x16x32_bf16(a1, bf, acc[1][nt], 0, 0, 0);
    }
  }

#pragma unroll
  for (int i = 0; i < 2; i++) {
    int mt = (i == 0) ? m0 : m1;
#pragma unroll
    for (int nt = 0; nt < 8; nt++) {
      int col = nt * 16 + am;
      float bv = bias_l[col];
#pragma unroll
      for (int rr = 0; rr < 4; rr++) {
        int row = mt + q * 4 + rr;
        if (row < N_NODES_C) {
          float v = acc[i][nt][rr] + bv;
          out[(size_t)row * DIM_C + col] = fmaxf(v, 0.f);
        }
      }
    }
  }
}

// --------------------------------------------------------------------------
extern "C" void kernel_launch(void* const* d_in, const int* in_sizes, int n_in,
                              void* d_out, int out_size, void* d_ws, size_t ws_size,
                              hipStream_t stream) {
  const float* h      = (const float*)d_in[0];
  const int*   src    = (const int*)d_in[1];
  const int*   dst    = (const int*)d_in[2];
  const float* Wself  = (const float*)d_in[4];
  const float* Wneigh = (const float*)d_in[5];
  const float* bias   = (const float*)d_in[6];
  float*       out    = (float*)d_out;

  char* ws = (char*)d_ws;
  ushort*        hb     = (ushort*)(ws + OFF_HB);
  ushort*        accb   = (ushort*)(ws + OFF_ACC);
  unsigned*      packed = (unsigned*)(ws + OFF_PK);
  int*           gcur   = (int*)(ws + OFF_GC);
  ushort*        wb     = (ushort*)(ws + OFF_WB);
  unsigned char* h8     = (unsigned char*)(ws + OFF_H8);

  // Zero the 1568 bin cursors only (6272 B); all else fully overwritten.
  hipMemsetAsync(gcur, 0, NBKT * sizeof(int), stream);

  sage_cast_bucket<<<NB_SCAT + NB_WCAST + NB_CASTK, 1024, 0, stream>>>(
      h, hb, h8, Wself, Wneigh, wb, src, dst, gcur, packed);
  sage_csr_gather <<<NBKT, 256, 0, stream>>>(packed, gcur, h8, accb);
  sage_gemm_mfma  <<<(N_NODES_C + 127) / 128, 256, 0, stream>>>(hb, accb, wb,
                                                                bias, out);
}